// Round 6
// baseline (598.565 us; speedup 1.0000x reference)
//
#include <hip/hip_runtime.h>

#define DEV __device__ __forceinline__

typedef float          f32x4  __attribute__((ext_vector_type(4)));
typedef __bf16         bf16x8 __attribute__((ext_vector_type(8)));
typedef unsigned short u16x8  __attribute__((ext_vector_type(8)));
typedef unsigned short u16x4  __attribute__((ext_vector_type(4)));

static constexpr int  Bq   = 256;   // batch
static constexpr int  Qs   = 128;   // seq len
static constexpr int  Dm   = 256;   // model dim
static constexpr int  Ff   = 512;   // ffn dim
static constexpr int  ROWS = Bq * Qs;               // 32768
static constexpr long QK_LSTR = (long)ROWS * 512;   // q||k history per layer (head-major)

DEV float b2f(unsigned short h) {
    unsigned int u = ((unsigned int)h) << 16;
    float f; __builtin_memcpy(&f, &u, 4); return f;
}
DEV unsigned short f2b(float f) {
    unsigned int u; __builtin_memcpy(&u, &f, 4);
    u += 0x7fffu + ((u >> 16) & 1u);   // RNE
    return (unsigned short)(u >> 16);
}
DEV f32x4 mfma_bf16(u16x8 a, u16x8 b, f32x4 c) {
    return __builtin_amdgcn_mfma_f32_16x16x32_bf16(
        __builtin_bit_cast(bf16x8, a), __builtin_bit_cast(bf16x8, b), c, 0, 0, 0);
}
// async global->LDS, 16B per lane; LDS dst must be wave-uniform base + lane*16
DEV void gl_lds16(const unsigned short* g, unsigned short* l) {
    __builtin_amdgcn_global_load_lds(
        (const __attribute__((address_space(1))) unsigned int*)g,
        (__attribute__((address_space(3))) unsigned int*)l, 16, 0, 0);
}

// ---------------- embed: z = x @ W_P + b_P + W_pos (all f32 in), bf16 out ----------------
__global__ void k_embed(const float* __restrict__ x,
                        const float* __restrict__ WP,
                        const float* __restrict__ bP,
                        const float* __restrict__ Wpos,
                        unsigned short* __restrict__ zb) {
    int row = blockIdx.x;            // b*Q + q
    int d   = threadIdx.x;           // 0..255
    int q   = row & (Qs - 1);
    const float* xr = x + row * 16;
    float acc = bP[d] + Wpos[q * Dm + d];
#pragma unroll
    for (int p = 0; p < 16; p++) acc += xr[p] * WP[p * Dm + d];
    zb[(long)row * Dm + d] = f2b(acc);
}

// ---------------- one-shot prep: weight transposes (bf16), fused bias pack, attn-bias pack ----------------
// Segment sizes
static constexpr int S0 = 3 * 768 * 256;   // wTqkv  [l][n(768)][k(256)], q-part scaled 0.25
static constexpr int S1 = 3 * 256 * 256;   // wTo    [l][n][k]
static constexpr int S2 = 3 * 512 * 256;   // wT1    [l][n(512)][k(256)]
static constexpr int S3 = 3 * 256 * 512;   // wT2    [l][n(256)][k(512)]
static constexpr int S4 = 3 * 768;         // bqkv f32, q-part scaled 0.25
static constexpr int S5 = 3 * 256 * 64;    // pb: packed attn bias, (l+1)*ab in accS register layout
static constexpr int PREP_TOT = S0 + S1 + S2 + S3 + S4 + S5;

__global__ void k_prep(const float* __restrict__ Wq, const float* __restrict__ Wk,
                       const float* __restrict__ Wv, const float* __restrict__ Wo,
                       const float* __restrict__ W1, const float* __restrict__ W2,
                       const float* __restrict__ bq, const float* __restrict__ bk,
                       const float* __restrict__ bv, const float* __restrict__ ab,
                       unsigned short* __restrict__ wTqkv, unsigned short* __restrict__ wTo,
                       unsigned short* __restrict__ wT1, unsigned short* __restrict__ wT2,
                       float* __restrict__ bqkv, float* __restrict__ pb) {
    int idx = blockIdx.x * 256 + threadIdx.x;
    if (idx < S0) {
        int l = idx / (768 * 256), r = idx % (768 * 256);
        int n = r / 256, k = r % 256;
        const float* W = (n < 256) ? Wq : (n < 512) ? Wk : Wv;
        float v = W[(long)l * 65536 + k * 256 + (n & 255)];
        if (n < 256) v *= 0.25f;            // fold DK^-0.5 into q
        wTqkv[idx] = f2b(v);
    } else if (idx < S0 + S1) {
        int j = idx - S0;
        int l = j / 65536, r = j % 65536, n = r / 256, k = r % 256;
        wTo[j] = f2b(Wo[(long)l * 65536 + k * 256 + n]);
    } else if (idx < S0 + S1 + S2) {
        int j = idx - S0 - S1;
        int l = j / (512 * 256), r = j % (512 * 256), n = r / 256, k = r % 256;
        wT1[j] = f2b(W1[(long)l * 131072 + k * 512 + n]);
    } else if (idx < S0 + S1 + S2 + S3) {
        int j = idx - S0 - S1 - S2;
        int l = j / (256 * 512), r = j % (256 * 512), n = r / 512, k = r % 512;
        wT2[j] = f2b(W2[(long)l * 131072 + k * 256 + n]);
    } else if (idx < S0 + S1 + S2 + S3 + S4) {
        int j = idx - S0 - S1 - S2 - S3;
        int l = j / 768, c = j % 768;
        float v = (c < 256) ? bq[l * 256 + c] * 0.25f
                : (c < 512) ? bk[l * 256 + c - 256]
                            : bv[l * 256 + c - 512];
        bqkv[j] = v;
    } else if (idx < PREP_TOT) {
        int j = idx - S0 - S1 - S2 - S3 - S4;
        int l = j / 16384, r = j % 16384;
        int t = r / 64, u = r % 64;
        int i = u >> 5, rr = (u >> 3) & 3, jj = u & 7;
        int wave = t >> 6, quad = (t >> 4) & 3, l16 = t & 15;
        int m = 32 * wave + 16 * i + 4 * quad + rr;
        int col = 16 * jj + l16;
        pb[j] = (float)(l + 1) * ab[m * 128 + col];
    }
}

// ---------------- GEMM: C = act(A[MxK] @ W[KxN] + bias), W given as WT[NxK] bf16 ----------------
// 128x128 tile, 4 waves 2x2, 16x16x32 bf16 MFMA, two BK=32 sub-tiles staged per barrier
// (validated m97 LDS layout, half the barrier drains). global_load_lds staging.
// MODE: 0 = bf16 out (stride N),
//       2 = qkv split: col<512 -> head-major qk history [b][h][{q,k}][row][dk], col>=512 -> v (stride 256)
template <int GELU, int MODE>
__global__ __launch_bounds__(256) void k_gemm(const unsigned short* __restrict__ A,
                                              const unsigned short* __restrict__ WT,
                                              const float* __restrict__ bias,
                                              unsigned short* __restrict__ outB,
                                              unsigned short* __restrict__ aux,
                                              int M, int N, int K) {
    __shared__ unsigned short As[2][128 * 32];
    __shared__ unsigned short Bs[2][128 * 32];
    const int tid  = threadIdx.x;
    const int wave = tid >> 6, lane = tid & 63, quad = lane >> 4, l16 = lane & 15;
    const int mq = wave >> 1, nq = wave & 1;
    const int m_blk = blockIdx.x * 128, n_blk = blockIdx.y * 128;
    const int c0 = tid, c1 = tid + 256;
    const int ra0 = c0 >> 2, ca0 = (c0 & 3) * 8;
    const int ra1 = c1 >> 2, ca1 = (c1 & 3) * 8;

    f32x4 acc[4][4] = {};

    for (int k0 = 0; k0 < K; k0 += 64) {
#pragma unroll
        for (int hh = 0; hh < 2; hh++) {
            int kk = k0 + hh * 32;
            gl_lds16(A  + (long)(m_blk + ra0) * K + kk + ca0, &As[hh][c0 * 8]);
            gl_lds16(A  + (long)(m_blk + ra1) * K + kk + ca1, &As[hh][c1 * 8]);
            gl_lds16(WT + (long)(n_blk + ra0) * K + kk + ca0, &Bs[hh][c0 * 8]);
            gl_lds16(WT + (long)(n_blk + ra1) * K + kk + ca1, &Bs[hh][c1 * 8]);
        }
        __syncthreads();
#pragma unroll
        for (int hh = 0; hh < 2; hh++) {
            u16x8 af[4], bf[4];
#pragma unroll
            for (int i = 0; i < 4; i++)
                af[i] = *(const u16x8*)&As[hh][(64 * mq + 16 * i + l16) * 32 + quad * 8];
#pragma unroll
            for (int j = 0; j < 4; j++)
                bf[j] = *(const u16x8*)&Bs[hh][(64 * nq + 16 * j + l16) * 32 + quad * 8];
#pragma unroll
            for (int i = 0; i < 4; i++)
#pragma unroll
                for (int j = 0; j < 4; j++)
                    acc[i][j] = mfma_bf16(af[i], bf[j], acc[i][j]);
        }
        __syncthreads();
    }

#pragma unroll
    for (int i = 0; i < 4; i++) {
        int row = m_blk + 64 * mq + 16 * i + quad * 4;   // C row = quad*4 + reg
#pragma unroll
        for (int j = 0; j < 4; j++) {
            int col = n_blk + 64 * nq + 16 * j + l16;    // C col = lane&15
            float bb = bias[col];
#pragma unroll
            for (int r = 0; r < 4; r++) {
                float v = acc[i][j][r] + bb;
                if (GELU) v = 0.5f * v * (1.0f + erff(v * 0.70710678118f));
                if (MODE == 0) outB[(long)(row + r) * N + col] = f2b(v);
                if (MODE == 2) {
                    int grow = row + r, b = grow >> 7, rin = grow & 127;
                    if (col < 512) {
                        int s = col >> 8, hh = (col >> 4) & 15, dk = col & 15;
                        outB[((long)((b * 16 + hh) * 2 + s)) * 2048 + rin * 16 + dk] = f2b(v);
                    } else {
                        aux[(long)grow * 256 + (col - 512)] = f2b(v);
                    }
                }
            }
        }
    }
}

// ---------------- fused GEMM + residual + LayerNorm ----------------
// C = LN( Zres + A[MxK] @ W[K x 256] + bias ; g, be ).  Tile 64 rows x 256 cols (full row).
template <int LAST>
__global__ __launch_bounds__(256) void k_gemm_ln(const unsigned short* __restrict__ A,
                                                 const unsigned short* __restrict__ WT,
                                                 const float* __restrict__ bias,
                                                 const unsigned short* __restrict__ Zres,
                                                 const float* __restrict__ g,
                                                 const float* __restrict__ be,
                                                 unsigned short* __restrict__ zb,
                                                 float* __restrict__ outF,
                                                 int K) {
    __shared__ unsigned short smem[16384 + 2048 + 8192];
    unsigned short* Zs = smem;
    unsigned short* As = smem + 16384;
    unsigned short* Bs = smem + 16384 + 2048;
    float2* stats = (float2*)(smem + 16384);   // aliases As after K-loop

    const int tid  = threadIdx.x;
    const int wave = tid >> 6, lane = tid & 63, quad = lane >> 4, l16 = lane & 15;
    const int m_blk = blockIdx.x * 64;

#pragma unroll
    for (int s = 0; s < 8; s++) {
        int c = tid + 256 * s;
        int zr = c >> 5, zc = (c & 31) * 8;
        gl_lds16(Zres + (long)(m_blk + zr) * 256 + zc, &Zs[c * 8]);
    }

    const int ca = (tid & 3) * 8, raA = tid >> 2;
    f32x4 acc[4][4] = {};

    for (int k0 = 0; k0 < K; k0 += 32) {
        gl_lds16(A + (long)(m_blk + raA) * K + k0 + ca, &As[tid * 8]);
#pragma unroll
        for (int s = 0; s < 4; s++) {
            int c = tid + 256 * s;
            int br = c >> 2, bc = (c & 3) * 8;
            gl_lds16(WT + (long)br * K + k0 + bc, &Bs[c * 8]);
        }
        __syncthreads();
        u16x8 af[4], bf[4];
#pragma unroll
        for (int i = 0; i < 4; i++)
            af[i] = *(const u16x8*)&As[(16 * i + l16) * 32 + quad * 8];
#pragma unroll
        for (int j = 0; j < 4; j++)
            bf[j] = *(const u16x8*)&Bs[(64 * wave + 16 * j + l16) * 32 + quad * 8];
#pragma unroll
        for (int i = 0; i < 4; i++)
#pragma unroll
            for (int j = 0; j < 4; j++)
                acc[i][j] = mfma_bf16(af[i], bf[j], acc[i][j]);
        __syncthreads();
    }

    float bb[4], gg[4], bt[4];
#pragma unroll
    for (int j = 0; j < 4; j++) {
        int col = 64 * wave + 16 * j + l16;
        bb[j] = bias[col]; gg[j] = g[col]; bt[j] = be[col];
    }
#pragma unroll
    for (int i = 0; i < 4; i++) {
#pragma unroll
        for (int r = 0; r < 4; r++) {
            int rloc = 16 * i + quad * 4 + r;
            float s1 = 0.f, s2 = 0.f;
#pragma unroll
            for (int j = 0; j < 4; j++) {
                int col = 64 * wave + 16 * j + l16;
                float v = acc[i][j][r] + bb[j] + b2f(Zs[rloc * 256 + col]);
                acc[i][j][r] = v;
                s1 += v; s2 += v * v;
            }
            for (int mk = 1; mk < 16; mk <<= 1) {
                s1 += __shfl_xor(s1, mk);
                s2 += __shfl_xor(s2, mk);
            }
            if (l16 == 0) stats[rloc * 4 + wave] = make_float2(s1, s2);
        }
    }
    __syncthreads();
#pragma unroll
    for (int i = 0; i < 4; i++) {
#pragma unroll
        for (int r = 0; r < 4; r++) {
            int rloc = 16 * i + quad * 4 + r;
            f32x4 p0 = *(const f32x4*)&stats[rloc * 4];
            f32x4 p1 = *(const f32x4*)&stats[rloc * 4 + 2];
            float S1 = p0[0] + p0[2] + p1[0] + p1[2];
            float S2 = p0[1] + p0[3] + p1[1] + p1[3];
            float mean = S1 * (1.0f / 256.0f);
            float var  = S2 * (1.0f / 256.0f) - mean * mean;
            float rstd = rsqrtf(var + 1e-5f);
            long grow = m_blk + rloc;
#pragma unroll
            for (int j = 0; j < 4; j++) {
                int col = 64 * wave + 16 * j + l16;
                float o = (acc[i][j][r] - mean) * rstd * gg[j] + bt[j];
                if (LAST) outF[grow * 256 + col] = o;
                else      zb[grow * 256 + col] = f2b(o);
            }
        }
    }
}

// ---------------- fused attention for layer L (score-carry recompute) ----------------
// grid = B*H blocks; block = 256 thr (4 waves, 32 S-rows each).
// qkh layout: [l][b][h][{q,k}][row(128)][dk(16)] bf16, q pre-scaled by 0.25.
// scores = carry(qk) + pb (packed (L+1)*bias); exp WITHOUT max-sub (|s| small by construction);
// P stored unnormalized; rowsum via ones-B MFMA; O normalized at epilogue.
template <int L>
__global__ __launch_bounds__(256) void k_attn(const unsigned short* __restrict__ qkh,
                                              const unsigned short* __restrict__ vbuf,
                                              const float* __restrict__ pb,
                                              unsigned short* __restrict__ o_out) {
    __shared__ unsigned short vt[16 * 136];   // v^T [dk][key]
    __shared__ unsigned short Ps[128 * 136];  // unnormalized probs, ld 136
    const int tid  = threadIdx.x;
    const int wave = tid >> 6, lane = tid & 63, quad = lane >> 4, l16 = lane & 15;
    const int b = blockIdx.x >> 4, h = blockIdx.x & 15;
    const int qrow = tid >> 1, half = tid & 1;

    u16x8 vv = *(const u16x8*)(vbuf + (long)(b * Qs + qrow) * 256 + h * 16 + half * 8);
    const float* pbt = pb + ((long)L * 256 + tid) * 64;

    f32x4 accS[2][8] = {};
    u16x8 zero = {};

    constexpr int FULL = (L + 1) / 2;
    constexpr bool HALF = ((L + 1) & 1) != 0;

#pragma unroll
    for (int p = 0; p < FULL; p++) {
        const unsigned short* q0 = qkh + ((long)(((2 * p) * Bq + b) * 16 + h) * 2) * 2048;
        const unsigned short* q1 = qkh + ((long)(((2 * p + 1) * Bq + b) * 16 + h) * 2) * 2048;
        const unsigned short* qsel = (quad < 2) ? q0 : q1;
        const unsigned short* ksel = (quad < 2) ? (q0 + 2048) : (q1 + 2048);
        const int koff = (quad & 1) * 8;
        u16x8 af[2], bf8[8];
#pragma unroll
        for (int i = 0; i < 2; i++) {
            int m = 32 * wave + 16 * i + l16;
            af[i] = *(const u16x8*)(qsel + m * 16 + koff);
        }
#pragma unroll
        for (int j = 0; j < 8; j++) {
            int n = 16 * j + l16;
            bf8[j] = *(const u16x8*)(ksel + n * 16 + koff);
        }
#pragma unroll
        for (int i = 0; i < 2; i++)
#pragma unroll
            for (int j = 0; j < 8; j++)
                accS[i][j] = mfma_bf16(af[i], bf8[j], accS[i][j]);
    }
    if (HALF) {
        const unsigned short* qt = qkh + ((long)((L * Bq + b) * 16 + h) * 2) * 2048;
        const unsigned short* kt = qt + 2048;
        u16x8 af[2], bf8[8];
#pragma unroll
        for (int i = 0; i < 2; i++) {
            int m = 32 * wave + 16 * i + l16;
            af[i] = (quad < 2) ? *(const u16x8*)(qt + m * 16 + quad * 8) : zero;
        }
#pragma unroll
        for (int j = 0; j < 8; j++) {
            int n = 16 * j + l16;
            bf8[j] = (quad < 2) ? *(const u16x8*)(kt + n * 16 + quad * 8) : zero;
        }
#pragma unroll
        for (int i = 0; i < 2; i++)
#pragma unroll
            for (int j = 0; j < 8; j++)
                accS[i][j] = mfma_bf16(af[i], bf8[j], accS[i][j]);
    }

    // stage v^T
#pragma unroll
    for (int jj = 0; jj < 8; jj++) vt[(half * 8 + jj) * 136 + qrow] = vv[jj];

    // exp(score + packed bias) -> Ps (unnormalized, bf16); no max-sub, no row reductions
#pragma unroll
    for (int i = 0; i < 2; i++) {
#pragma unroll
        for (int r = 0; r < 4; r++) {
            int m = 32 * wave + 16 * i + quad * 4 + r;
            f32x4 p0 = *(const f32x4*)(pbt + (i * 4 + r) * 8);
            f32x4 p1 = *(const f32x4*)(pbt + (i * 4 + r) * 8 + 4);
#pragma unroll
            for (int j = 0; j < 8; j++) {
                float s = accS[i][j][r] + (j < 4 ? p0[j] : p1[j - 4]);
                Ps[m * 136 + 16 * j + l16] = f2b(__expf(s));
            }
        }
    }
    __syncthreads();

    // O = P @ v (and rowsum via ones-B MFMA): M=128, N=16, K=128
    f32x4 accO[2] = {};
    f32x4 accR[2] = {};
    u16x8 ones;
#pragma unroll
    for (int jj = 0; jj < 8; jj++) ones[jj] = 0x3F80;   // bf16 1.0
#pragma unroll
    for (int s = 0; s < 4; s++) {
        u16x8 bv = *(const u16x8*)&vt[l16 * 136 + s * 32 + quad * 8];
#pragma unroll
        for (int i = 0; i < 2; i++) {
            u16x8 ap = *(const u16x8*)&Ps[(32 * wave + 16 * i + l16) * 136 + s * 32 + quad * 8];
            accO[i] = mfma_bf16(ap, bv, accO[i]);
            accR[i] = mfma_bf16(ap, ones, accR[i]);
        }
    }
#pragma unroll
    for (int i = 0; i < 2; i++)
#pragma unroll
        for (int r = 0; r < 4; r++) {
            int m = 32 * wave + 16 * i + quad * 4 + r;
            float inv = __builtin_amdgcn_rcpf(accR[i][r]);
            o_out[(long)(b * Qs + m) * Dm + h * 16 + l16] = f2b(accO[i][r] * inv);
        }
}

extern "C" void kernel_launch(void* const* d_in, const int* in_sizes, int n_in,
                              void* d_out, int out_size, void* d_ws, size_t ws_size,
                              hipStream_t stream) {
    const float* x     = (const float*)d_in[0];
    const float* abias = (const float*)d_in[1];
    const float* WP    = (const float*)d_in[2];
    const float* bP    = (const float*)d_in[3];
    const float* Wpos  = (const float*)d_in[4];
    const float* Wq    = (const float*)d_in[5];
    const float* bqp   = (const float*)d_in[6];
    const float* Wk    = (const float*)d_in[7];
    const float* bkp   = (const float*)d_in[8];
    const float* Wv    = (const float*)d_in[9];
    const float* bvp   = (const float*)d_in[10];
    const float* Wo    = (const float*)d_in[11];
    const float* bo    = (const float*)d_in[12];
    const float* g1    = (const float*)d_in[13];
    const float* be1   = (const float*)d_in[14];
    const float* W1    = (const float*)d_in[15];
    const float* b1    = (const float*)d_in[16];
    const float* W2    = (const float*)d_in[17];
    const float* b2    = (const float*)d_in[18];
    const float* g2    = (const float*)d_in[19];
    const float* be2   = (const float*)d_in[20];
    (void)in_sizes; (void)n_in; (void)out_size; (void)ws_size;

    char* ws = (char*)d_ws;
    size_t off = 0;
    auto alloc = [&](size_t bytes) -> char* {
        char* p = ws + off; off += (bytes + 255) & ~(size_t)255; return p;
    };
    // ~172 MB of workspace
    unsigned short* z_b   = (unsigned short*)alloc((size_t)ROWS * Dm * 2);      // 16.8 MB
    unsigned short* qkh   = (unsigned short*)alloc((size_t)3 * ROWS * 512 * 2); // 100.7 MB head-major
    unsigned short* v_cur = (unsigned short*)alloc((size_t)ROWS * Dm * 2);      // 16.8 MB
    unsigned short* h1    = (unsigned short*)alloc((size_t)ROWS * Ff * 2);      // 33.5 MB
    unsigned short* o_b   = h1;   // alias: o_b dead before h1 is written
    unsigned short* wTqkv = (unsigned short*)alloc((size_t)S0 * 2);
    unsigned short* wTo   = (unsigned short*)alloc((size_t)S1 * 2);
    unsigned short* wT1   = (unsigned short*)alloc((size_t)S2 * 2);
    unsigned short* wT2   = (unsigned short*)alloc((size_t)S3 * 2);
    float*          bqkv  = (float*)alloc((size_t)S4 * 4);
    float*          pb    = (float*)alloc((size_t)S5 * 4);

    k_prep<<<(PREP_TOT + 255) / 256, 256, 0, stream>>>(
        Wq, Wk, Wv, Wo, W1, W2, bqp, bkp, bvp, abias,
        wTqkv, wTo, wT1, wT2, bqkv, pb);
    k_embed<<<ROWS, 256, 0, stream>>>(x, WP, bP, Wpos, z_b);

    for (int l = 0; l < 3; l++) {
        // fused QKV projection: N = 768, split epilogue -> head-major qk history + v
        k_gemm<0, 2><<<dim3(ROWS / 128, 6), 256, 0, stream>>>(
            z_b, wTqkv + (long)l * 768 * 256, bqkv + l * 768,
            qkh + (long)l * QK_LSTR, v_cur, ROWS, 768, 256);
        // attention with score-carry recompute (layer-packed K)
        if (l == 0)      k_attn<0><<<Bq * 16, 256, 0, stream>>>(qkh, v_cur, pb, o_b);
        else if (l == 1) k_attn<1><<<Bq * 16, 256, 0, stream>>>(qkh, v_cur, pb, o_b);
        else             k_attn<2><<<Bq * 16, 256, 0, stream>>>(qkh, v_cur, pb, o_b);
        // O projection + residual + LN1 (fused), bf16 residual stream
        k_gemm_ln<0><<<ROWS / 64, 256, 0, stream>>>(
            o_b, wTo + (long)l * 256 * 256, bo + l * 256, z_b,
            g1 + l * 256, be1 + l * 256, z_b, nullptr, 256);
        // FFN1 (gelu)
        k_gemm<1, 0><<<dim3(ROWS / 128, 4), 256, 0, stream>>>(
            z_b, wT1 + (long)l * 512 * 256, b1 + l * 512, h1, nullptr, ROWS, 512, 256);
        // FFN2 + residual + LN2 (fused); last layer writes f32 d_out
        if (l == 2)
            k_gemm_ln<1><<<ROWS / 64, 256, 0, stream>>>(
                h1, wT2 + (long)l * 256 * 512, b2 + l * 256, z_b,
                g2 + l * 256, be2 + l * 256, nullptr, (float*)d_out, 512);
        else
            k_gemm_ln<0><<<ROWS / 64, 256, 0, stream>>>(
                h1, wT2 + (long)l * 256 * 512, b2 + l * 256, z_b,
                g2 + l * 256, be2 + l * 256, z_b, nullptr, 512);
    }
}

// Round 7
// 546.706 us; speedup vs baseline: 1.0949x; 1.0949x over previous
//
#include <hip/hip_runtime.h>

#define DEV __device__ __forceinline__

typedef float          f32x4  __attribute__((ext_vector_type(4)));
typedef __bf16         bf16x8 __attribute__((ext_vector_type(8)));
typedef unsigned short u16x8  __attribute__((ext_vector_type(8)));
typedef unsigned short u16x4  __attribute__((ext_vector_type(4)));

static constexpr int  Bq   = 256;   // batch
static constexpr int  Qs   = 128;   // seq len
static constexpr int  Dm   = 256;   // model dim
static constexpr int  Ff   = 512;   // ffn dim
static constexpr int  ROWS = Bq * Qs;               // 32768
static constexpr long QK_LSTR = (long)ROWS * 512;   // q||k history per layer (head-major)

DEV float b2f(unsigned short h) {
    unsigned int u = ((unsigned int)h) << 16;
    float f; __builtin_memcpy(&f, &u, 4); return f;
}
DEV unsigned short f2b(float f) {
    unsigned int u; __builtin_memcpy(&u, &f, 4);
    u += 0x7fffu + ((u >> 16) & 1u);   // RNE
    return (unsigned short)(u >> 16);
}
DEV f32x4 mfma_bf16(u16x8 a, u16x8 b, f32x4 c) {
    return __builtin_amdgcn_mfma_f32_16x16x32_bf16(
        __builtin_bit_cast(bf16x8, a), __builtin_bit_cast(bf16x8, b), c, 0, 0, 0);
}
// async global->LDS, 16B per lane; LDS dst must be wave-uniform base + lane*16
DEV void gl_lds16(const unsigned short* g, unsigned short* l) {
    __builtin_amdgcn_global_load_lds(
        (const __attribute__((address_space(1))) unsigned int*)g,
        (__attribute__((address_space(3))) unsigned int*)l, 16, 0, 0);
}

// ---------------- embed: z = x @ W_P + b_P + W_pos (all f32 in), bf16 out ----------------
__global__ void k_embed(const float* __restrict__ x,
                        const float* __restrict__ WP,
                        const float* __restrict__ bP,
                        const float* __restrict__ Wpos,
                        unsigned short* __restrict__ zb) {
    int row = blockIdx.x;            // b*Q + q
    int d   = threadIdx.x;           // 0..255
    int q   = row & (Qs - 1);
    const float* xr = x + row * 16;
    float acc = bP[d] + Wpos[q * Dm + d];
#pragma unroll
    for (int p = 0; p < 16; p++) acc += xr[p] * WP[p * Dm + d];
    zb[(long)row * Dm + d] = f2b(acc);
}

// ---------------- one-shot prep: weight transposes (bf16), fused bias pack, attn-bias pack ----------------
static constexpr int S0 = 3 * 768 * 256;   // wTqkv  [l][n(768)][k(256)], q-part scaled 0.25
static constexpr int S1 = 3 * 256 * 256;   // wTo    [l][n][k]
static constexpr int S2 = 3 * 512 * 256;   // wT1    [l][n(512)][k(256)]
static constexpr int S3 = 3 * 256 * 512;   // wT2    [l][n(256)][k(512)]
static constexpr int S4 = 3 * 768;         // bqkv f32, q-part scaled 0.25
static constexpr int S5 = 3 * 64 * 256;    // pb: packed attn bias, [l][u(64)][tid(256)] (coalesced)
static constexpr int PREP_TOT = S0 + S1 + S2 + S3 + S4 + S5;

__global__ void k_prep(const float* __restrict__ Wq, const float* __restrict__ Wk,
                       const float* __restrict__ Wv, const float* __restrict__ Wo,
                       const float* __restrict__ W1, const float* __restrict__ W2,
                       const float* __restrict__ bq, const float* __restrict__ bk,
                       const float* __restrict__ bv, const float* __restrict__ ab,
                       unsigned short* __restrict__ wTqkv, unsigned short* __restrict__ wTo,
                       unsigned short* __restrict__ wT1, unsigned short* __restrict__ wT2,
                       float* __restrict__ bqkv, float* __restrict__ pb) {
    int idx = blockIdx.x * 256 + threadIdx.x;
    if (idx < S0) {
        int l = idx / (768 * 256), r = idx % (768 * 256);
        int n = r / 256, k = r % 256;
        const float* W = (n < 256) ? Wq : (n < 512) ? Wk : Wv;
        float v = W[(long)l * 65536 + k * 256 + (n & 255)];
        if (n < 256) v *= 0.25f;            // fold DK^-0.5 into q
        wTqkv[idx] = f2b(v);
    } else if (idx < S0 + S1) {
        int j = idx - S0;
        int l = j / 65536, r = j % 65536, n = r / 256, k = r % 256;
        wTo[j] = f2b(Wo[(long)l * 65536 + k * 256 + n]);
    } else if (idx < S0 + S1 + S2) {
        int j = idx - S0 - S1;
        int l = j / (512 * 256), r = j % (512 * 256), n = r / 256, k = r % 256;
        wT1[j] = f2b(W1[(long)l * 131072 + k * 512 + n]);
    } else if (idx < S0 + S1 + S2 + S3) {
        int j = idx - S0 - S1 - S2;
        int l = j / (256 * 512), r = j % (256 * 512), n = r / 512, k = r % 512;
        wT2[j] = f2b(W2[(long)l * 131072 + k * 256 + n]);
    } else if (idx < S0 + S1 + S2 + S3 + S4) {
        int j = idx - S0 - S1 - S2 - S3;
        int l = j / 768, c = j % 768;
        float v = (c < 256) ? bq[l * 256 + c] * 0.25f
                : (c < 512) ? bk[l * 256 + c - 256]
                            : bv[l * 256 + c - 512];
        bqkv[j] = v;
    } else if (idx < PREP_TOT) {
        // pb[l][u][t]: value u for thread t, layer l  (lane-coalesced reads in k_attn)
        int j = idx - S0 - S1 - S2 - S3 - S4;
        int l = j / 16384, r = j % 16384;
        int u = r / 256, t = r % 256;
        int i = u >> 5, rr = (u >> 3) & 3, jj = u & 7;
        int wave = t >> 6, quad = (t >> 4) & 3, l16 = t & 15;
        int m = 32 * wave + 16 * i + 4 * quad + rr;
        int col = 16 * jj + l16;
        pb[j] = (float)(l + 1) * ab[m * 128 + col];
    }
}

// ---------------- GEMM: C = act(A[MxK] @ W[KxN] + bias), W given as WT[NxK] bf16 ----------------
// 128x128 tile, 4 waves 2x2, 16x16x32 bf16 MFMA, two BK=32 sub-tiles staged per barrier.
// MODE: 0 = bf16 out (stride N),
//       2 = qkv split: col<512 -> head-major qk history [b][h][{q,k}][row][dk], col>=512 -> v (stride 256)
template <int GELU, int MODE>
__global__ __launch_bounds__(256) void k_gemm(const unsigned short* __restrict__ A,
                                              const unsigned short* __restrict__ WT,
                                              const float* __restrict__ bias,
                                              unsigned short* __restrict__ outB,
                                              unsigned short* __restrict__ aux,
                                              int M, int N, int K) {
    __shared__ unsigned short As[2][128 * 32];
    __shared__ unsigned short Bs[2][128 * 32];
    const int tid  = threadIdx.x;
    const int wave = tid >> 6, lane = tid & 63, quad = lane >> 4, l16 = lane & 15;
    const int mq = wave >> 1, nq = wave & 1;
    const int m_blk = blockIdx.x * 128, n_blk = blockIdx.y * 128;
    const int c0 = tid, c1 = tid + 256;
    const int ra0 = c0 >> 2, ca0 = (c0 & 3) * 8;
    const int ra1 = c1 >> 2, ca1 = (c1 & 3) * 8;

    f32x4 acc[4][4] = {};

    for (int k0 = 0; k0 < K; k0 += 64) {
#pragma unroll
        for (int hh = 0; hh < 2; hh++) {
            int kk = k0 + hh * 32;
            gl_lds16(A  + (long)(m_blk + ra0) * K + kk + ca0, &As[hh][c0 * 8]);
            gl_lds16(A  + (long)(m_blk + ra1) * K + kk + ca1, &As[hh][c1 * 8]);
            gl_lds16(WT + (long)(n_blk + ra0) * K + kk + ca0, &Bs[hh][c0 * 8]);
            gl_lds16(WT + (long)(n_blk + ra1) * K + kk + ca1, &Bs[hh][c1 * 8]);
        }
        __syncthreads();
#pragma unroll
        for (int hh = 0; hh < 2; hh++) {
            u16x8 af[4], bf[4];
#pragma unroll
            for (int i = 0; i < 4; i++)
                af[i] = *(const u16x8*)&As[hh][(64 * mq + 16 * i + l16) * 32 + quad * 8];
#pragma unroll
            for (int j = 0; j < 4; j++)
                bf[j] = *(const u16x8*)&Bs[hh][(64 * nq + 16 * j + l16) * 32 + quad * 8];
#pragma unroll
            for (int i = 0; i < 4; i++)
#pragma unroll
                for (int j = 0; j < 4; j++)
                    acc[i][j] = mfma_bf16(af[i], bf[j], acc[i][j]);
        }
        __syncthreads();
    }

#pragma unroll
    for (int i = 0; i < 4; i++) {
        int row = m_blk + 64 * mq + 16 * i + quad * 4;   // C row = quad*4 + reg
#pragma unroll
        for (int j = 0; j < 4; j++) {
            int col = n_blk + 64 * nq + 16 * j + l16;    // C col = lane&15
            float bb = bias[col];
#pragma unroll
            for (int r = 0; r < 4; r++) {
                float v = acc[i][j][r] + bb;
                if (GELU) v = 0.5f * v * (1.0f + erff(v * 0.70710678118f));
                if (MODE == 0) outB[(long)(row + r) * N + col] = f2b(v);
                if (MODE == 2) {
                    int grow = row + r, b = grow >> 7, rin = grow & 127;
                    if (col < 512) {
                        int s = col >> 8, hh = (col >> 4) & 15, dk = col & 15;
                        outB[((long)((b * 16 + hh) * 2 + s)) * 2048 + rin * 16 + dk] = f2b(v);
                    } else {
                        aux[(long)grow * 256 + (col - 512)] = f2b(v);
                    }
                }
            }
        }
    }
}

// ---------------- fused GEMM + residual + LayerNorm ----------------
// C = LN( Zres + A[MxK] @ W[K x 256] + bias ; g, be ).  Tile 64 rows x 256 cols (full row).
template <int LAST>
__global__ __launch_bounds__(256) void k_gemm_ln(const unsigned short* __restrict__ A,
                                                 const unsigned short* __restrict__ WT,
                                                 const float* __restrict__ bias,
                                                 const unsigned short* __restrict__ Zres,
                                                 const float* __restrict__ g,
                                                 const float* __restrict__ be,
                                                 unsigned short* __restrict__ zb,
                                                 float* __restrict__ outF,
                                                 int K) {
    __shared__ unsigned short smem[16384 + 2048 + 8192];
    unsigned short* Zs = smem;
    unsigned short* As = smem + 16384;
    unsigned short* Bs = smem + 16384 + 2048;
    float2* stats = (float2*)(smem + 16384);   // aliases As after K-loop

    const int tid  = threadIdx.x;
    const int wave = tid >> 6, lane = tid & 63, quad = lane >> 4, l16 = lane & 15;
    const int m_blk = blockIdx.x * 64;

#pragma unroll
    for (int s = 0; s < 8; s++) {
        int c = tid + 256 * s;
        int zr = c >> 5, zc = (c & 31) * 8;
        gl_lds16(Zres + (long)(m_blk + zr) * 256 + zc, &Zs[c * 8]);
    }

    const int ca = (tid & 3) * 8, raA = tid >> 2;
    f32x4 acc[4][4] = {};

    for (int k0 = 0; k0 < K; k0 += 32) {
        gl_lds16(A + (long)(m_blk + raA) * K + k0 + ca, &As[tid * 8]);
#pragma unroll
        for (int s = 0; s < 4; s++) {
            int c = tid + 256 * s;
            int br = c >> 2, bc = (c & 3) * 8;
            gl_lds16(WT + (long)br * K + k0 + bc, &Bs[c * 8]);
        }
        __syncthreads();
        u16x8 af[4], bf[4];
#pragma unroll
        for (int i = 0; i < 4; i++)
            af[i] = *(const u16x8*)&As[(16 * i + l16) * 32 + quad * 8];
#pragma unroll
        for (int j = 0; j < 4; j++)
            bf[j] = *(const u16x8*)&Bs[(64 * wave + 16 * j + l16) * 32 + quad * 8];
#pragma unroll
        for (int i = 0; i < 4; i++)
#pragma unroll
            for (int j = 0; j < 4; j++)
                acc[i][j] = mfma_bf16(af[i], bf[j], acc[i][j]);
        __syncthreads();
    }

    float bb[4], gg[4], bt[4];
#pragma unroll
    for (int j = 0; j < 4; j++) {
        int col = 64 * wave + 16 * j + l16;
        bb[j] = bias[col]; gg[j] = g[col]; bt[j] = be[col];
    }
#pragma unroll
    for (int i = 0; i < 4; i++) {
#pragma unroll
        for (int r = 0; r < 4; r++) {
            int rloc = 16 * i + quad * 4 + r;
            float s1 = 0.f, s2 = 0.f;
#pragma unroll
            for (int j = 0; j < 4; j++) {
                int col = 64 * wave + 16 * j + l16;
                float v = acc[i][j][r] + bb[j] + b2f(Zs[rloc * 256 + col]);
                acc[i][j][r] = v;
                s1 += v; s2 += v * v;
            }
            for (int mk = 1; mk < 16; mk <<= 1) {
                s1 += __shfl_xor(s1, mk);
                s2 += __shfl_xor(s2, mk);
            }
            if (l16 == 0) stats[rloc * 4 + wave] = make_float2(s1, s2);
        }
    }
    __syncthreads();
#pragma unroll
    for (int i = 0; i < 4; i++) {
#pragma unroll
        for (int r = 0; r < 4; r++) {
            int rloc = 16 * i + quad * 4 + r;
            f32x4 p0 = *(const f32x4*)&stats[rloc * 4];
            f32x4 p1 = *(const f32x4*)&stats[rloc * 4 + 2];
            float S1 = p0[0] + p0[2] + p1[0] + p1[2];
            float S2 = p0[1] + p0[3] + p1[1] + p1[3];
            float mean = S1 * (1.0f / 256.0f);
            float var  = S2 * (1.0f / 256.0f) - mean * mean;
            float rstd = rsqrtf(var + 1e-5f);
            long grow = m_blk + rloc;
#pragma unroll
            for (int j = 0; j < 4; j++) {
                int col = 64 * wave + 16 * j + l16;
                float o = (acc[i][j][r] - mean) * rstd * gg[j] + bt[j];
                if (LAST) outF[grow * 256 + col] = o;
                else      zb[grow * 256 + col] = f2b(o);
            }
        }
    }
}

// ---------------- fused attention for layer L (score-carry recompute) ----------------
// grid = B*H blocks; block = 256 thr (4 waves, 32 S-rows each).
// qkh layout: [l][b][h][{q,k}][row(128)][dk(16)] bf16, q pre-scaled by 0.25.
// scores = carry(qk) + pb (packed (L+1)*bias, [u][tid] coalesced); exp w/o max-sub;
// P unnormalized; rowsum via ones-B MFMA; O normalized at epilogue.
template <int L>
__global__ __launch_bounds__(256) void k_attn(const unsigned short* __restrict__ qkh,
                                              const unsigned short* __restrict__ vbuf,
                                              const float* __restrict__ pb,
                                              unsigned short* __restrict__ o_out) {
    __shared__ unsigned short vt[16 * 136];   // v^T [dk][key]
    __shared__ unsigned short Ps[128 * 136];  // unnormalized probs, ld 136
    const int tid  = threadIdx.x;
    const int wave = tid >> 6, lane = tid & 63, quad = lane >> 4, l16 = lane & 15;
    const int b = blockIdx.x >> 4, h = blockIdx.x & 15;
    const int qrow = tid >> 1, half = tid & 1;

    u16x8 vv = *(const u16x8*)(vbuf + (long)(b * Qs + qrow) * 256 + h * 16 + half * 8);
    const float* pbt = pb + (long)L * 16384 + tid;   // value u at pbt[u*256], lane-coalesced

    f32x4 accS[2][8] = {};
    u16x8 zero = {};

    constexpr int FULL = (L + 1) / 2;
    constexpr bool HALF = ((L + 1) & 1) != 0;

#pragma unroll
    for (int p = 0; p < FULL; p++) {
        const unsigned short* q0 = qkh + ((long)(((2 * p) * Bq + b) * 16 + h) * 2) * 2048;
        const unsigned short* q1 = qkh + ((long)(((2 * p + 1) * Bq + b) * 16 + h) * 2) * 2048;
        const unsigned short* qsel = (quad < 2) ? q0 : q1;
        const unsigned short* ksel = (quad < 2) ? (q0 + 2048) : (q1 + 2048);
        const int koff = (quad & 1) * 8;
        u16x8 af[2], bf8[8];
#pragma unroll
        for (int i = 0; i < 2; i++) {
            int m = 32 * wave + 16 * i + l16;
            af[i] = *(const u16x8*)(qsel + m * 16 + koff);
        }
#pragma unroll
        for (int j = 0; j < 8; j++) {
            int n = 16 * j + l16;
            bf8[j] = *(const u16x8*)(ksel + n * 16 + koff);
        }
#pragma unroll
        for (int i = 0; i < 2; i++)
#pragma unroll
            for (int j = 0; j < 8; j++)
                accS[i][j] = mfma_bf16(af[i], bf8[j], accS[i][j]);
    }
    if (HALF) {
        const unsigned short* qt = qkh + ((long)((L * Bq + b) * 16 + h) * 2) * 2048;
        const unsigned short* kt = qt + 2048;
        u16x8 af[2], bf8[8];
#pragma unroll
        for (int i = 0; i < 2; i++) {
            int m = 32 * wave + 16 * i + l16;
            af[i] = (quad < 2) ? *(const u16x8*)(qt + m * 16 + quad * 8) : zero;
        }
#pragma unroll
        for (int j = 0; j < 8; j++) {
            int n = 16 * j + l16;
            bf8[j] = (quad < 2) ? *(const u16x8*)(kt + n * 16 + quad * 8) : zero;
        }
#pragma unroll
        for (int i = 0; i < 2; i++)
#pragma unroll
            for (int j = 0; j < 8; j++)
                accS[i][j] = mfma_bf16(af[i], bf8[j], accS[i][j]);
    }

    // stage v^T
#pragma unroll
    for (int jj = 0; jj < 8; jj++) vt[(half * 8 + jj) * 136 + qrow] = vv[jj];

    // exp(score + packed bias) -> Ps (unnormalized, bf16); no max-sub, no row reductions
#pragma unroll
    for (int i = 0; i < 2; i++) {
#pragma unroll
        for (int r = 0; r < 4; r++) {
            int m = 32 * wave + 16 * i + quad * 4 + r;
#pragma unroll
            for (int j = 0; j < 8; j++) {
                int u = (i * 4 + r) * 8 + j;
                float s = accS[i][j][r] + pbt[u * 256];
                Ps[m * 136 + 16 * j + l16] = f2b(__expf(s));
            }
        }
    }
    __syncthreads();

    // O = P @ v (and rowsum via ones-B MFMA): M=128, N=16, K=128
    f32x4 accO[2] = {};
    f32x4 accR[2] = {};
    u16x8 ones;
#pragma unroll
    for (int jj = 0; jj < 8; jj++) ones[jj] = 0x3F80;   // bf16 1.0
#pragma unroll
    for (int s = 0; s < 4; s++) {
        u16x8 bv = *(const u16x8*)&vt[l16 * 136 + s * 32 + quad * 8];
#pragma unroll
        for (int i = 0; i < 2; i++) {
            u16x8 ap = *(const u16x8*)&Ps[(32 * wave + 16 * i + l16) * 136 + s * 32 + quad * 8];
            accO[i] = mfma_bf16(ap, bv, accO[i]);
            accR[i] = mfma_bf16(ap, ones, accR[i]);
        }
    }
#pragma unroll
    for (int i = 0; i < 2; i++)
#pragma unroll
        for (int r = 0; r < 4; r++) {
            int m = 32 * wave + 16 * i + quad * 4 + r;
            float inv = __builtin_amdgcn_rcpf(accR[i][r]);
            o_out[(long)(b * Qs + m) * Dm + h * 16 + l16] = f2b(accO[i][r] * inv);
        }
}

extern "C" void kernel_launch(void* const* d_in, const int* in_sizes, int n_in,
                              void* d_out, int out_size, void* d_ws, size_t ws_size,
                              hipStream_t stream) {
    const float* x     = (const float*)d_in[0];
    const float* abias = (const float*)d_in[1];
    const float* WP    = (const float*)d_in[2];
    const float* bP    = (const float*)d_in[3];
    const float* Wpos  = (const float*)d_in[4];
    const float* Wq    = (const float*)d_in[5];
    const float* bqp   = (const float*)d_in[6];
    const float* Wk    = (const float*)d_in[7];
    const float* bkp   = (const float*)d_in[8];
    const float* Wv    = (const float*)d_in[9];
    const float* bvp   = (const float*)d_in[10];
    const float* Wo    = (const float*)d_in[11];
    const float* bo    = (const float*)d_in[12];
    const float* g1    = (const float*)d_in[13];
    const float* be1   = (const float*)d_in[14];
    const float* W1    = (const float*)d_in[15];
    const float* b1    = (const float*)d_in[16];
    const float* W2    = (const float*)d_in[17];
    const float* b2    = (const float*)d_in[18];
    const float* g2    = (const float*)d_in[19];
    const float* be2   = (const float*)d_in[20];
    (void)in_sizes; (void)n_in; (void)out_size; (void)ws_size;

    char* ws = (char*)d_ws;
    size_t off = 0;
    auto alloc = [&](size_t bytes) -> char* {
        char* p = ws + off; off += (bytes + 255) & ~(size_t)255; return p;
    };
    // ~172 MB of workspace
    unsigned short* z_b   = (unsigned short*)alloc((size_t)ROWS * Dm * 2);      // 16.8 MB
    unsigned short* qkh   = (unsigned short*)alloc((size_t)3 * ROWS * 512 * 2); // 100.7 MB head-major
    unsigned short* v_cur = (unsigned short*)alloc((size_t)ROWS * Dm * 2);      // 16.8 MB
    unsigned short* h1    = (unsigned short*)alloc((size_t)ROWS * Ff * 2);      // 33.5 MB
    unsigned short* o_b   = h1;   // alias: o_b dead before h1 is written
    unsigned short* wTqkv = (unsigned short*)alloc((size_t)S0 * 2);
    unsigned short* wTo   = (unsigned short*)alloc((size_t)S1 * 2);
    unsigned short* wT1   = (unsigned short*)alloc((size_t)S2 * 2);
    unsigned short* wT2   = (unsigned short*)alloc((size_t)S3 * 2);
    float*          bqkv  = (float*)alloc((size_t)S4 * 4);
    float*          pb    = (float*)alloc((size_t)S5 * 4);

    k_prep<<<(PREP_TOT + 255) / 256, 256, 0, stream>>>(
        Wq, Wk, Wv, Wo, W1, W2, bqp, bkp, bvp, abias,
        wTqkv, wTo, wT1, wT2, bqkv, pb);
    k_embed<<<ROWS, 256, 0, stream>>>(x, WP, bP, Wpos, z_b);

    for (int l = 0; l < 3; l++) {
        // fused QKV projection: N = 768, split epilogue -> head-major qk history + v
        k_gemm<0, 2><<<dim3(ROWS / 128, 6), 256, 0, stream>>>(
            z_b, wTqkv + (long)l * 768 * 256, bqkv + l * 768,
            qkh + (long)l * QK_LSTR, v_cur, ROWS, 768, 256);
        // attention with score-carry recompute (layer-packed K)
        if (l == 0)      k_attn<0><<<Bq * 16, 256, 0, stream>>>(qkh, v_cur, pb, o_b);
        else if (l == 1) k_attn<1><<<Bq * 16, 256, 0, stream>>>(qkh, v_cur, pb, o_b);
        else             k_attn<2><<<Bq * 16, 256, 0, stream>>>(qkh, v_cur, pb, o_b);
        // O projection + residual + LN1 (fused), bf16 residual stream
        k_gemm_ln<0><<<ROWS / 64, 256, 0, stream>>>(
            o_b, wTo + (long)l * 256 * 256, bo + l * 256, z_b,
            g1 + l * 256, be1 + l * 256, z_b, nullptr, 256);
        // FFN1 (gelu)
        k_gemm<1, 0><<<dim3(ROWS / 128, 4), 256, 0, stream>>>(
            z_b, wT1 + (long)l * 512 * 256, b1 + l * 512, h1, nullptr, ROWS, 512, 256);
        // FFN2 + residual + LN2 (fused); last layer writes f32 d_out
        if (l == 2)
            k_gemm_ln<1><<<ROWS / 64, 256, 0, stream>>>(
                h1, wT2 + (long)l * 256 * 512, b2 + l * 256, z_b,
                g2 + l * 256, be2 + l * 256, nullptr, (float*)d_out, 512);
        else
            k_gemm_ln<0><<<ROWS / 64, 256, 0, stream>>>(
                h1, wT2 + (long)l * 256 * 512, b2 + l * 256, z_b,
                g2 + l * 256, be2 + l * 256, z_b, nullptr, 512);
    }
}